// Round 1
// 98.178 us; speedup vs baseline: 1.0589x; 1.0589x over previous
//
#include <hip/hip_runtime.h>
#include <stdint.h>

// Problem constants (B=2, T=1024 -> N=2048 tokens; D=H=1024; E=8; top-2)
#define D_DIM 1024
#define H_DIM 1024
#define NE 8
#define NTOK 2048
#define SB 5120            // shared-expert slot base (expert slots padded to 128: max 40*128)
#define TOTAL_ROWS 7168    // 5120 + 2048
#define GEMM_BLKS 448      // 8 XCD groups x 56 max (mslot, n0) pairs (56 = 40 expert + 16 shared tiles)
#define CONV2_BLKS 4608    // w2 + cproj conversion blocks fused into GEMM1 launch
#define M8 (8 * 1024 * 1024)

typedef __bf16 bf16;
typedef bf16 bf16x8 __attribute__((ext_vector_type(8)));
typedef float f32x4 __attribute__((ext_vector_type(4)));

// async global->LDS, 16B per lane. LDS dest is wave-uniform base + lane*16
// (we pass the per-lane pointer; lane0's value is the wave base).
#define GL16(SRC, DST)                                               \
  __builtin_amdgcn_global_load_lds(                                  \
      (const __attribute__((address_space(1))) void*)(SRC),          \
      (__attribute__((address_space(3))) void*)(DST), 16, 0, 0)

// ---- workspace layout (bytes) ----
#define WS_NTILES     0           // [0]=ntiles, [1]=pairs per XCD group (= ntiles)
#define WS_TILE_E     64          // 128 ints
#define WS_TILE_BASE  576         // 128 ints
#define WS_EIDX       2048        // 4096 ints
#define WS_WTOK       18432      // 4096 floats
#define WS_TOK        34816      // 7168 ints
#define WS_SLOT       63488      // 4096 ints
#define WS_XG         131072     // 7168*1024 bf16; GEMM1 input, then reused as eo (GEMM2 out)
#define WS_HID        16777216   // 7168*1024 bf16
#define WS_W1B        33554432   // 16 MB
#define WS_W2B        50331648   // 16 MB
#define WS_CFCB       67108864   // 2 MB
#define WS_CPROJB     69206016   // 2 MB (end 71,303,168)

// ---- fused: blocks [0,512) run the router (4 tokens/block, wave per token);
//      blocks [512, 5120) convert ONLY w1 + cfc (GEMM1's weights) to bf16.
//      w2 + cproj conversion is deferred into the GEMM1 launch (overlap). ----
__global__ __launch_bounds__(256) void convrouter(
    const float* __restrict__ x, const float* __restrict__ gw,
    const float* __restrict__ lb, int* __restrict__ eidx,
    float* __restrict__ wtok, bf16* __restrict__ xg,
    const float* __restrict__ w1, const float* __restrict__ cfc,
    bf16* __restrict__ w1b, bf16* __restrict__ cfcb) {
  const int bx = blockIdx.x;
  if (bx >= 512) {
    // ---- weight conversion path (w1: 8M elems, cfc: 1M elems) ----
    int i = ((bx - 512) * 256 + threadIdx.x) * 8;
    const float* s;
    bf16* d;
    if (i < M8) { s = w1 + i;        d = w1b + i; }
    else        { s = cfc + (i - M8); d = cfcb + (i - M8); }
    float4 a = *(const float4*)(s);
    float4 b = *(const float4*)(s + 4);
    union { uint4 v; bf16 h[8]; } t;
    t.h[0] = (bf16)a.x; t.h[1] = (bf16)a.y; t.h[2] = (bf16)a.z; t.h[3] = (bf16)a.w;
    t.h[4] = (bf16)b.x; t.h[5] = (bf16)b.y; t.h[6] = (bf16)b.z; t.h[7] = (bf16)b.w;
    *(uint4*)(d) = t.v;
    return;
  }
  // ---- router path ----
  const int wave = threadIdx.x >> 6;
  const int lane = threadIdx.x & 63;
  const int n = bx * 4 + wave;

  const float4* xr = (const float4*)(x + (size_t)n * D_DIM);
  float4 xv[4];
#pragma unroll
  for (int q = 0; q < 4; q++) xv[q] = xr[q * 64 + lane];

  float acc[NE];
#pragma unroll
  for (int e = 0; e < NE; e++) acc[e] = 0.f;
#pragma unroll
  for (int e = 0; e < NE; e++) {
    const float4* gr = (const float4*)(gw + e * D_DIM);
#pragma unroll
    for (int q = 0; q < 4; q++) {
      float4 g = gr[q * 64 + lane];
      acc[e] += xv[q].x * g.x + xv[q].y * g.y + xv[q].z * g.z + xv[q].w * g.w;
    }
  }

  bf16* dst = xg + (size_t)n * D_DIM;
#pragma unroll
  for (int q = 0; q < 4; q++) {
    union { ushort4 u; bf16 h[4]; } t;
    t.h[0] = (bf16)xv[q].x; t.h[1] = (bf16)xv[q].y;
    t.h[2] = (bf16)xv[q].z; t.h[3] = (bf16)xv[q].w;
    *(ushort4*)(dst + (q * 64 + lane) * 4) = t.u;
  }

#pragma unroll
  for (int e = 0; e < NE; e++)
#pragma unroll
    for (int off = 32; off > 0; off >>= 1) acc[e] += __shfl_xor(acc[e], off, 64);

  if (lane == 0) {
    float b[NE];
#pragma unroll
    for (int e = 0; e < NE; e++) b[e] = acc[e] + lb[e];
    int i0 = 0; float v0 = b[0];
#pragma unroll
    for (int e = 1; e < NE; e++) if (b[e] > v0) { v0 = b[e]; i0 = e; }
    int i1 = -1; float v1 = -3.4e38f;
#pragma unroll
    for (int e = 0; e < NE; e++) if (e != i0 && b[e] > v1) { v1 = b[e]; i1 = e; }
    float s0 = 1.f / (1.f + expf(-acc[i0]));
    float s1 = 1.f / (1.f + expf(-acc[i1]));
    float s = s0 + s1 + 1e-6f;
    eidx[n * 2] = i0;     wtok[n * 2] = s0 / s;
    eidx[n * 2 + 1] = i1; wtok[n * 2 + 1] = s1 / s;
  }
}

// ---- assign: single block. Ballot-aggregated per-expert positions, 128-row
// tile table, tok table, token->slot map, XCD partition size. ----
__global__ __launch_bounds__(256) void assign_kernel(
    const int* __restrict__ eidx, int* __restrict__ tE, int* __restrict__ tB,
    int* __restrict__ ntiles, int* __restrict__ tok,
    int* __restrict__ slotIdx) {
  __shared__ int segCnt[64][NE];
  __shared__ int segBase[64][NE];
  const int tid = threadIdx.x;
  const int wave = tid >> 6, lane = tid & 63;
  const unsigned long long below = (lane == 0) ? 0ull : ((~0ull) >> (64 - lane));

  int e16[16], pr16[16];
#pragma unroll
  for (int t = 0; t < 16; t++) {
    const int r = t * 256 + tid;
    const int seg = t * 4 + wave;
    const int e = eidx[r];
    int prior = 0;
#pragma unroll
    for (int ee = 0; ee < NE; ee++) {
      unsigned long long m = __ballot(e == ee);
      if (e == ee) prior = __popcll(m & below);
      if (lane == ee) segCnt[seg][ee] = __popcll(m);
    }
    e16[t] = e; pr16[t] = prior;
  }

  // tok init: pads -> token 0; shared region -> identity
  for (int s = tid; s < TOTAL_ROWS; s += 256) {
    tok[s] = (s < SB) ? 0 : (s - SB);
  }
  __syncthreads();

  if (wave == 0) {
    int v[NE], inc[NE];
#pragma unroll
    for (int e = 0; e < NE; e++) { v[e] = segCnt[lane][e]; inc[e] = v[e]; }
#pragma unroll
    for (int off = 1; off < 64; off <<= 1) {
#pragma unroll
      for (int e = 0; e < NE; e++) {
        int u = __shfl_up(inc[e], off);
        if (lane >= off) inc[e] += u;
      }
    }
    int tot[NE];
#pragma unroll
    for (int e = 0; e < NE; e++) tot[e] = __shfl(inc[e], 63);
    int offsL[NE]; int b = 0;
#pragma unroll
    for (int e = 0; e < NE; e++) { offsL[e] = b; b += ((tot[e] + 127) >> 7) << 7; }
#pragma unroll
    for (int e = 0; e < NE; e++) segBase[lane][e] = offsL[e] + (inc[e] - v[e]);
    if (lane == 0) {
      int nt = 0;
      for (int e = 0; e < NE; e++) {
        int t128 = (tot[e] + 127) >> 7;
        for (int t = 0; t < t128; t++) { tE[nt] = e; tB[nt] = offsL[e] + t * 128; nt++; }
      }
      for (int t = 0; t < 16; t++) { tE[nt] = NE; tB[nt] = SB + t * 128; nt++; }
      ntiles[0] = nt;
      ntiles[1] = nt;   // pairs per XCD group: nt*8 N-blocks / 8 groups
    }
  }
  __syncthreads();

#pragma unroll
  for (int t = 0; t < 16; t++) {
    const int r = t * 256 + tid;
    const int seg = t * 4 + wave;
    const int slot = segBase[seg][e16[t]] + pr16[t];
    tok[slot] = r >> 1;
    slotIdx[r] = slot;
  }
}

// ---- table-driven 128x128 bf16 GEMM (C = A·B^T), BK=32, double-buffered LDS,
// global_load_lds width=16 staging (m97 structure: ~874-912 TF measured on
// gfx950 for this shape). 4 waves, each computes 64x64 via 4x4 of 16x16x32
// MFMA fragments. Bank conflicts: linear LDS dest (required by gload_lds) +
// inverse-XOR-swizzled GLOBAL source chunk + same swizzle on ds_read
// (involution chunk ^= (row>>1)&3) -> 2-way max = free.
// XCD-AWARE PARTITION: bid%8 = XCD slot; each XCD group takes a contiguous
// chunk of the expert-sorted (mslot,n0) pair list so its ~2 experts' weights
// stay L2-resident.
// MODE 0: A gathered via tok[] from xg; relu^2 -> bf16 store to hid. Blocks
//         [GEMM_BLKS, GEMM_BLKS+CONV2_BLKS) instead convert w2+cproj fp32->bf16
//         (overlaps memory-bound conversion under compute-bound GEMM).
// MODE 1: A direct from hid; plain bf16 store to eo (slot space). ----
template <int MODE>
__global__ __launch_bounds__(256) void moe_gemm(
    const bf16* __restrict__ Ab, const bf16* __restrict__ We,
    const bf16* __restrict__ Ws, const int* __restrict__ tE,
    const int* __restrict__ tB, const int* __restrict__ ntp,
    bf16* __restrict__ Cout, const int* __restrict__ tok,
    const float* __restrict__ cvs1, const float* __restrict__ cvs2,
    bf16* __restrict__ cvd1, bf16* __restrict__ cvd2) {
  if (MODE == 0 && blockIdx.x >= GEMM_BLKS) {
    // ---- fused w2 + cproj conversion (8M + 1M elems) ----
    int i = ((blockIdx.x - GEMM_BLKS) * 256 + threadIdx.x) * 8;
    const float* s;
    bf16* d;
    if (i < M8) { s = cvs1 + i;        d = cvd1 + i; }
    else        { s = cvs2 + (i - M8); d = cvd2 + (i - M8); }
    float4 a = *(const float4*)(s);
    float4 b = *(const float4*)(s + 4);
    union { uint4 v; bf16 h[8]; } t;
    t.h[0] = (bf16)a.x; t.h[1] = (bf16)a.y; t.h[2] = (bf16)a.z; t.h[3] = (bf16)a.w;
    t.h[4] = (bf16)b.x; t.h[5] = (bf16)b.y; t.h[6] = (bf16)b.z; t.h[7] = (bf16)b.w;
    *(uint4*)(d) = t.v;
    return;
  }

  const int per = ntp[1];
  const int g = blockIdx.x & 7, idx = blockIdx.x >> 3;
  if (idx >= per) return;
  const int p = g * per + idx;
  const int mslot = p >> 3;
  const int n0 = (p & 7) * 128;
  const int e = tE[mslot];
  const int base = tB[mslot];
  const bf16* Bp = (e < NE) ? (We + (size_t)e * (H_DIM * D_DIM)) : Ws;

  __shared__ bf16 As[2 * 4096];   // 2 x 128x32 bf16 = 16 KB
  __shared__ bf16 Bs[2 * 4096];   // 2 x 128x32 bf16 = 16 KB

  const int tid = threadIdx.x;
  const int wave = tid >> 6, lane = tid & 63;

  // staging: thread t covers rows (t>>2) and 64+(t>>2), chunk slot t&3.
  // source chunk is XOR-swizzled; LDS dest is linear (lane-contiguous 16B).
  const int rS = tid >> 2, sS = tid & 3;
  const int cS = sS ^ ((rS >> 1) & 3);   // same for rS and rS+64 (64>>1 ≡ 0 mod 4)
  size_t rowA1, rowA2;
  if (MODE == 0) { rowA1 = tok[base + rS]; rowA2 = tok[base + 64 + rS]; }
  else           { rowA1 = base + rS;      rowA2 = base + 64 + rS; }
  const bf16* gA1 = Ab + rowA1 * 1024 + cS * 8;
  const bf16* gA2 = Ab + rowA2 * 1024 + cS * 8;
  const bf16* gB1 = Bp + (size_t)(n0 + rS) * 1024 + cS * 8;
  const bf16* gB2 = Bp + (size_t)(n0 + 64 + rS) * 1024 + cS * 8;
  bf16* laBase = As + tid * 8;   // byte addr = wavebase + lane*16 (lane-linear)
  bf16* lbBase = Bs + tid * 8;

  // fragment read offsets (swizzled)
  const int wm = (wave >> 1) * 64, wn = (wave & 1) * 64;
  const int fr = lane & 15, chk = lane >> 4;
  int aOff[4], bOff[4];
#pragma unroll
  for (int i = 0; i < 4; i++) {
    const int r = wm + i * 16 + fr;
    aOff[i] = r * 32 + ((chk ^ ((r >> 1) & 3)) * 8);
  }
#pragma unroll
  for (int j = 0; j < 4; j++) {
    const int r = wn + j * 16 + fr;
    bOff[j] = r * 32 + ((chk ^ ((r >> 1) & 3)) * 8);
  }

  const f32x4 zero = {0.f, 0.f, 0.f, 0.f};
  f32x4 acc[4][4];
#pragma unroll
  for (int i = 0; i < 4; i++)
#pragma unroll
    for (int j = 0; j < 4; j++) acc[i][j] = zero;

  // prologue: stage tile 0 into buffer 0
  GL16(gA1, laBase);
  GL16(gA2, laBase + 2048);
  GL16(gB1, lbBase);
  GL16(gB2, lbBase + 2048);

  for (int kt = 0; kt < 32; ++kt) {
    const int cur = kt & 1;
    __syncthreads();   // drains vmcnt(0): tile kt landed in LDS[cur]
    if (kt + 1 < 32) {
      // issue tile kt+1 into the other buffer; stays in flight under compute
      const int koff = (kt + 1) * 32;
      const int bo = (cur ^ 1) * 4096;
      GL16(gA1 + koff, laBase + bo);
      GL16(gA2 + koff, laBase + bo + 2048);
      GL16(gB1 + koff, lbBase + bo);
      GL16(gB2 + koff, lbBase + bo + 2048);
    }
    bf16x8 af[4], bv[4];
#pragma unroll
    for (int i = 0; i < 4; i++) af[i] = *(const bf16x8*)&As[cur * 4096 + aOff[i]];
#pragma unroll
    for (int j = 0; j < 4; j++) bv[j] = *(const bf16x8*)&Bs[cur * 4096 + bOff[j]];
#pragma unroll
    for (int i = 0; i < 4; i++)
#pragma unroll
      for (int j = 0; j < 4; j++)
        acc[i][j] = __builtin_amdgcn_mfma_f32_16x16x32_bf16(af[i], bv[j],
                                                            acc[i][j], 0, 0, 0);
  }

  const int rbase = (lane >> 4) * 4;
#pragma unroll
  for (int i = 0; i < 4; i++) {
#pragma unroll
    for (int j = 0; j < 4; j++) {
      const int col = n0 + wn + j * 16 + fr;
#pragma unroll
      for (int r = 0; r < 4; r++) {
        const int orow = wm + i * 16 + rbase + r;
        float v = acc[i][j][r];
        if (MODE == 0) v = v > 0.f ? v * v : 0.f;
        Cout[(size_t)(base + orow) * 1024 + col] = (bf16)v;
      }
    }
  }
}

// ---- combine: out[t] = w0*eo[s0] + w1*eo[s1] + eo[SB+t]. One block/token. ----
__global__ __launch_bounds__(256) void combine_kernel(
    const bf16* __restrict__ eo, const int* __restrict__ slotIdx,
    const float* __restrict__ wtok, float* __restrict__ out) {
  const int t = blockIdx.x;
  const int c = threadIdx.x * 4;
  const int s0 = slotIdx[t * 2], s1 = slotIdx[t * 2 + 1];
  const float w0 = wtok[t * 2], w1 = wtok[t * 2 + 1];
  union U { uint2 v; bf16 h[4]; };
  U a, b, sh;
  a.v  = *(const uint2*)(eo + (size_t)s0 * 1024 + c);
  b.v  = *(const uint2*)(eo + (size_t)s1 * 1024 + c);
  sh.v = *(const uint2*)(eo + (size_t)(SB + t) * 1024 + c);
  float4 o;
  o.x = w0 * (float)a.h[0] + w1 * (float)b.h[0] + (float)sh.h[0];
  o.y = w0 * (float)a.h[1] + w1 * (float)b.h[1] + (float)sh.h[1];
  o.z = w0 * (float)a.h[2] + w1 * (float)b.h[2] + (float)sh.h[2];
  o.w = w0 * (float)a.h[3] + w1 * (float)b.h[3] + (float)sh.h[3];
  *(float4*)(out + (size_t)t * 1024 + c) = o;
}

extern "C" void kernel_launch(void* const* d_in, const int* in_sizes, int n_in,
                              void* d_out, int out_size, void* d_ws,
                              size_t ws_size, hipStream_t stream) {
  const float* x     = (const float*)d_in[0];
  const float* gw    = (const float*)d_in[1];
  const float* lb    = (const float*)d_in[2];
  const float* w1    = (const float*)d_in[3];
  const float* w2    = (const float*)d_in[4];
  const float* cfc   = (const float*)d_in[5];
  const float* cproj = (const float*)d_in[6];
  float* out = (float*)d_out;
  char* ws = (char*)d_ws;

  int*   ntl   = (int*)(ws + WS_NTILES);
  int*   tE    = (int*)(ws + WS_TILE_E);
  int*   tB    = (int*)(ws + WS_TILE_BASE);
  int*   eidx  = (int*)(ws + WS_EIDX);
  float* wtok  = (float*)(ws + WS_WTOK);
  int*   tok   = (int*)(ws + WS_TOK);
  int*   slotI = (int*)(ws + WS_SLOT);
  bf16*  xg    = (bf16*)(ws + WS_XG);     // GEMM1 input; reused as eo for GEMM2 out
  bf16*  hid   = (bf16*)(ws + WS_HID);
  bf16*  w1b   = (bf16*)(ws + WS_W1B);
  bf16*  w2b   = (bf16*)(ws + WS_W2B);
  bf16*  cfcb  = (bf16*)(ws + WS_CFCB);
  bf16*  cprojb= (bf16*)(ws + WS_CPROJB);

  // router + (w1, cfc) conversion only — w2/cproj conversion rides inside GEMM1
  convrouter<<<5120, 256, 0, stream>>>(x, gw, lb, eidx, wtok, xg,
                                       w1, cfc, w1b, cfcb);
  assign_kernel<<<1, 256, 0, stream>>>(eidx, tE, tB, ntl, tok, slotI);

  moe_gemm<0><<<GEMM_BLKS + CONV2_BLKS, 256, 0, stream>>>(
      xg, w1b, cfcb, tE, tB, ntl, hid, tok, w2, cproj, w2b, cprojb);
  moe_gemm<1><<<GEMM_BLKS, 256, 0, stream>>>(
      hid, w2b, cprojb, tE, tB, ntl, xg, tok, nullptr, nullptr, nullptr, nullptr);
  combine_kernel<<<NTOK, 256, 0, stream>>>(xg, slotI, wtok, out);
}

// Round 2
// 82.933 us; speedup vs baseline: 1.2535x; 1.1838x over previous
//
#include <hip/hip_runtime.h>
#include <stdint.h>

// Problem constants (B=2, T=1024 -> N=2048 tokens; D=H=1024; E=8; top-2)
#define D_DIM 1024
#define H_DIM 1024
#define NE 8
#define NTOK 2048
#define SB 5120            // shared-expert slot base (expert slots padded to 128: max 40*128)
#define TOTAL_ROWS 7168    // 5120 + 2048
#define GEMM_BLKS 448      // 8 XCD groups x 56 max (mslot, n0) pairs (56 = 40 expert + 16 shared tiles)
#define CONV2_BLKS 4608    // w2 + cproj conversion blocks fused into GEMM1 launch
#define M8 (8 * 1024 * 1024)

typedef __bf16 bf16;
typedef bf16 bf16x8 __attribute__((ext_vector_type(8)));
typedef float f32x4 __attribute__((ext_vector_type(4)));

// async global->LDS, 16B per lane. LDS dest is wave-uniform base + lane*16
// (we pass the per-lane pointer; lane0's value is the wave base).
#define GL16(SRC, DST)                                               \
  __builtin_amdgcn_global_load_lds(                                  \
      (const __attribute__((address_space(1))) void*)(SRC),          \
      (__attribute__((address_space(3))) void*)(DST), 16, 0, 0)

// ---- workspace layout (bytes) ----
#define WS_NTILES     0           // [0]=ntiles, [1]=pairs per XCD group (= ntiles)
#define WS_TILE_E     64          // 128 ints
#define WS_TILE_BASE  576         // 128 ints
#define WS_EIDX       2048        // 4096 ints
#define WS_WTOK       18432      // 4096 floats
#define WS_TOK        34816      // 7168 ints
#define WS_SLOT       63488      // 4096 ints
#define WS_XG         131072     // 7168*1024 bf16; GEMM1 input, then reused as eo (GEMM2 out)
#define WS_HID        16777216   // 7168*1024 bf16
#define WS_W1B        33554432   // 16 MB
#define WS_W2B        50331648   // 16 MB
#define WS_CFCB       67108864   // 2 MB
#define WS_CPROJB     69206016   // 2 MB (end 71,303,168)

// ---- fused: blocks [0,512) run the router (4 tokens/block, wave per token);
//      blocks [512, 5120) convert ONLY w1 + cfc (GEMM1's weights) to bf16.
//      w2 + cproj conversion is deferred into the GEMM1 launch (overlap). ----
__global__ __launch_bounds__(256) void convrouter(
    const float* __restrict__ x, const float* __restrict__ gw,
    const float* __restrict__ lb, int* __restrict__ eidx,
    float* __restrict__ wtok, bf16* __restrict__ xg,
    const float* __restrict__ w1, const float* __restrict__ cfc,
    bf16* __restrict__ w1b, bf16* __restrict__ cfcb) {
  const int bx = blockIdx.x;
  if (bx >= 512) {
    // ---- weight conversion path (w1: 8M elems, cfc: 1M elems) ----
    int i = ((bx - 512) * 256 + threadIdx.x) * 8;
    const float* s;
    bf16* d;
    if (i < M8) { s = w1 + i;        d = w1b + i; }
    else        { s = cfc + (i - M8); d = cfcb + (i - M8); }
    float4 a = *(const float4*)(s);
    float4 b = *(const float4*)(s + 4);
    union { uint4 v; bf16 h[8]; } t;
    t.h[0] = (bf16)a.x; t.h[1] = (bf16)a.y; t.h[2] = (bf16)a.z; t.h[3] = (bf16)a.w;
    t.h[4] = (bf16)b.x; t.h[5] = (bf16)b.y; t.h[6] = (bf16)b.z; t.h[7] = (bf16)b.w;
    *(uint4*)(d) = t.v;
    return;
  }
  // ---- router path ----
  const int wave = threadIdx.x >> 6;
  const int lane = threadIdx.x & 63;
  const int n = bx * 4 + wave;

  const float4* xr = (const float4*)(x + (size_t)n * D_DIM);
  float4 xv[4];
#pragma unroll
  for (int q = 0; q < 4; q++) xv[q] = xr[q * 64 + lane];

  float acc[NE];
#pragma unroll
  for (int e = 0; e < NE; e++) acc[e] = 0.f;
#pragma unroll
  for (int e = 0; e < NE; e++) {
    const float4* gr = (const float4*)(gw + e * D_DIM);
#pragma unroll
    for (int q = 0; q < 4; q++) {
      float4 g = gr[q * 64 + lane];
      acc[e] += xv[q].x * g.x + xv[q].y * g.y + xv[q].z * g.z + xv[q].w * g.w;
    }
  }

  bf16* dst = xg + (size_t)n * D_DIM;
#pragma unroll
  for (int q = 0; q < 4; q++) {
    union { ushort4 u; bf16 h[4]; } t;
    t.h[0] = (bf16)xv[q].x; t.h[1] = (bf16)xv[q].y;
    t.h[2] = (bf16)xv[q].z; t.h[3] = (bf16)xv[q].w;
    *(ushort4*)(dst + (q * 64 + lane) * 4) = t.u;
  }

#pragma unroll
  for (int e = 0; e < NE; e++)
#pragma unroll
    for (int off = 32; off > 0; off >>= 1) acc[e] += __shfl_xor(acc[e], off, 64);

  if (lane == 0) {
    float b[NE];
#pragma unroll
    for (int e = 0; e < NE; e++) b[e] = acc[e] + lb[e];
    int i0 = 0; float v0 = b[0];
#pragma unroll
    for (int e = 1; e < NE; e++) if (b[e] > v0) { v0 = b[e]; i0 = e; }
    int i1 = -1; float v1 = -3.4e38f;
#pragma unroll
    for (int e = 0; e < NE; e++) if (e != i0 && b[e] > v1) { v1 = b[e]; i1 = e; }
    float s0 = 1.f / (1.f + expf(-acc[i0]));
    float s1 = 1.f / (1.f + expf(-acc[i1]));
    float s = s0 + s1 + 1e-6f;
    eidx[n * 2] = i0;     wtok[n * 2] = s0 / s;
    eidx[n * 2 + 1] = i1; wtok[n * 2 + 1] = s1 / s;
  }
}

// ---- assign: single block. Ballot-aggregated per-expert positions, 128-row
// tile table, tok table, token->slot map, XCD partition size. ----
__global__ __launch_bounds__(256) void assign_kernel(
    const int* __restrict__ eidx, int* __restrict__ tE, int* __restrict__ tB,
    int* __restrict__ ntiles, int* __restrict__ tok,
    int* __restrict__ slotIdx) {
  __shared__ int segCnt[64][NE];
  __shared__ int segBase[64][NE];
  const int tid = threadIdx.x;
  const int wave = tid >> 6, lane = tid & 63;
  const unsigned long long below = (lane == 0) ? 0ull : ((~0ull) >> (64 - lane));

  int e16[16], pr16[16];
#pragma unroll
  for (int t = 0; t < 16; t++) {
    const int r = t * 256 + tid;
    const int seg = t * 4 + wave;
    const int e = eidx[r];
    int prior = 0;
#pragma unroll
    for (int ee = 0; ee < NE; ee++) {
      unsigned long long m = __ballot(e == ee);
      if (e == ee) prior = __popcll(m & below);
      if (lane == ee) segCnt[seg][ee] = __popcll(m);
    }
    e16[t] = e; pr16[t] = prior;
  }

  // tok init: pads -> token 0; shared region -> identity
  for (int s = tid; s < TOTAL_ROWS; s += 256) {
    tok[s] = (s < SB) ? 0 : (s - SB);
  }
  __syncthreads();

  if (wave == 0) {
    int v[NE], inc[NE];
#pragma unroll
    for (int e = 0; e < NE; e++) { v[e] = segCnt[lane][e]; inc[e] = v[e]; }
#pragma unroll
    for (int off = 1; off < 64; off <<= 1) {
#pragma unroll
      for (int e = 0; e < NE; e++) {
        int u = __shfl_up(inc[e], off);
        if (lane >= off) inc[e] += u;
      }
    }
    int tot[NE];
#pragma unroll
    for (int e = 0; e < NE; e++) tot[e] = __shfl(inc[e], 63);
    int offsL[NE]; int b = 0;
#pragma unroll
    for (int e = 0; e < NE; e++) { offsL[e] = b; b += ((tot[e] + 127) >> 7) << 7; }
#pragma unroll
    for (int e = 0; e < NE; e++) segBase[lane][e] = offsL[e] + (inc[e] - v[e]);
    if (lane == 0) {
      int nt = 0;
      for (int e = 0; e < NE; e++) {
        int t128 = (tot[e] + 127) >> 7;
        for (int t = 0; t < t128; t++) { tE[nt] = e; tB[nt] = offsL[e] + t * 128; nt++; }
      }
      for (int t = 0; t < 16; t++) { tE[nt] = NE; tB[nt] = SB + t * 128; nt++; }
      ntiles[0] = nt;
      ntiles[1] = nt;   // pairs per XCD group: nt*8 N-blocks / 8 groups
    }
  }
  __syncthreads();

#pragma unroll
  for (int t = 0; t < 16; t++) {
    const int r = t * 256 + tid;
    const int seg = t * 4 + wave;
    const int slot = segBase[seg][e16[t]] + pr16[t];
    tok[slot] = r >> 1;
    slotIdx[r] = slot;
  }
}

// ---- table-driven 128x128 bf16 GEMM (C = A·B^T), BK=32.
// TRIPLE-buffered LDS + counted-vmcnt pipeline (T3/T4): each tile's
// global_load_lds is issued 3 iterations ahead of its use, so ~600-900 cycles
// of load latency hide under compute WITHOUT relying on block co-residency
// (grid is only 448 blocks -> ~1.75 blocks/CU; the old vmcnt(0)-drain
// __syncthreads stalled every iteration at MfmaUtil 11%).
// Per iter: vmcnt(8) -> barrier -> ds_read frags -> lgkmcnt(0) -> barrier ->
// issue tile kt+3 -> setprio(1) MFMA x16 setprio(0). Epilogue peels vmcnt(4/0).
// Bank conflicts: linear LDS dest (gload_lds requirement) + inverse-XOR-
// swizzled GLOBAL source chunk + same swizzle on ds_read (involution
// chunk ^= (row>>1)&3) -> 2-way max = free.
// XCD-AWARE PARTITION: bid%8 = XCD slot; contiguous chunk of expert-sorted
// (mslot,n0) pairs per XCD so its ~2 experts' weights stay L2-resident.
// MODE 0: A gathered via tok[] from xg; relu^2 -> bf16 store to hid. Blocks
//         [GEMM_BLKS, GEMM_BLKS+CONV2_BLKS) instead convert w2+cproj
//         fp32->bf16 (overlaps memory-bound conversion under the GEMM).
// MODE 1: A direct from hid; plain bf16 store to eo (slot space). ----
template <int MODE>
__global__ __launch_bounds__(256) void moe_gemm(
    const bf16* __restrict__ Ab, const bf16* __restrict__ We,
    const bf16* __restrict__ Ws, const int* __restrict__ tE,
    const int* __restrict__ tB, const int* __restrict__ ntp,
    bf16* __restrict__ Cout, const int* __restrict__ tok,
    const float* __restrict__ cvs1, const float* __restrict__ cvs2,
    bf16* __restrict__ cvd1, bf16* __restrict__ cvd2) {
  if (MODE == 0 && blockIdx.x >= GEMM_BLKS) {
    // ---- fused w2 + cproj conversion (8M + 1M elems) ----
    int i = ((blockIdx.x - GEMM_BLKS) * 256 + threadIdx.x) * 8;
    const float* s;
    bf16* d;
    if (i < M8) { s = cvs1 + i;        d = cvd1 + i; }
    else        { s = cvs2 + (i - M8); d = cvd2 + (i - M8); }
    float4 a = *(const float4*)(s);
    float4 b = *(const float4*)(s + 4);
    union { uint4 v; bf16 h[8]; } t;
    t.h[0] = (bf16)a.x; t.h[1] = (bf16)a.y; t.h[2] = (bf16)a.z; t.h[3] = (bf16)a.w;
    t.h[4] = (bf16)b.x; t.h[5] = (bf16)b.y; t.h[6] = (bf16)b.z; t.h[7] = (bf16)b.w;
    *(uint4*)(d) = t.v;
    return;
  }

  const int per = ntp[1];
  const int g = blockIdx.x & 7, idx = blockIdx.x >> 3;
  if (idx >= per) return;
  const int p = g * per + idx;
  const int mslot = p >> 3;
  const int n0 = (p & 7) * 128;
  const int e = tE[mslot];
  const int base = tB[mslot];
  const bf16* Bp = (e < NE) ? (We + (size_t)e * (H_DIM * D_DIM)) : Ws;

  __shared__ bf16 As[3 * 4096];   // 3 x 128x32 bf16 = 24 KB
  __shared__ bf16 Bs[3 * 4096];   // 3 x 128x32 bf16 = 24 KB

  const int tid = threadIdx.x;
  const int wave = tid >> 6, lane = tid & 63;

  // staging: thread t covers rows (t>>2) and 64+(t>>2), chunk slot t&3.
  // source chunk is XOR-swizzled; LDS dest is linear (lane-contiguous 16B).
  const int rS = tid >> 2, sS = tid & 3;
  const int cS = sS ^ ((rS >> 1) & 3);   // same for rS and rS+64 (64>>1 ≡ 0 mod 4)
  size_t rowA1, rowA2;
  if (MODE == 0) { rowA1 = tok[base + rS]; rowA2 = tok[base + 64 + rS]; }
  else           { rowA1 = base + rS;      rowA2 = base + 64 + rS; }
  const bf16* gA1 = Ab + rowA1 * 1024 + cS * 8;
  const bf16* gA2 = Ab + rowA2 * 1024 + cS * 8;
  const bf16* gB1 = Bp + (size_t)(n0 + rS) * 1024 + cS * 8;
  const bf16* gB2 = Bp + (size_t)(n0 + 64 + rS) * 1024 + cS * 8;
  bf16* laBase = As + tid * 8;   // byte addr = wavebase + lane*16 (lane-linear)
  bf16* lbBase = Bs + tid * 8;

  // fragment read offsets (swizzled)
  const int wm = (wave >> 1) * 64, wn = (wave & 1) * 64;
  const int fr = lane & 15, chk = lane >> 4;
  int aOff[4], bOff[4];
#pragma unroll
  for (int i = 0; i < 4; i++) {
    const int r = wm + i * 16 + fr;
    aOff[i] = r * 32 + ((chk ^ ((r >> 1) & 3)) * 8);
  }
#pragma unroll
  for (int j = 0; j < 4; j++) {
    const int r = wn + j * 16 + fr;
    bOff[j] = r * 32 + ((chk ^ ((r >> 1) & 3)) * 8);
  }

  const f32x4 zero = {0.f, 0.f, 0.f, 0.f};
  f32x4 acc[4][4];
#pragma unroll
  for (int i = 0; i < 4; i++)
#pragma unroll
    for (int j = 0; j < 4; j++) acc[i][j] = zero;

  // prologue: stage tiles 0,1,2 into buffers 0,1,2 (12 loads in flight)
#pragma unroll
  for (int t = 0; t < 3; ++t) {
    const int ko = t * 32;
    const int bo = t * 4096;
    GL16(gA1 + ko, laBase + bo);
    GL16(gA2 + ko, laBase + bo + 2048);
    GL16(gB1 + ko, lbBase + bo);
    GL16(gB2 + ko, lbBase + bo + 2048);
  }

  int cur = 0;
  // per-iteration body. VMSTR: literal vmcnt immediate; ISSUE: stage kt+3.
#define GEMM_ITER(KT, VMSTR, ISSUE)                                           \
  {                                                                           \
    asm volatile("s_waitcnt vmcnt(" VMSTR ")" ::: "memory");                  \
    __builtin_amdgcn_s_barrier();          /* tile KT fully in LDS[cur] */    \
    __builtin_amdgcn_sched_barrier(0);                                        \
    bf16x8 af[4], bv[4];                                                      \
    _Pragma("unroll") for (int i = 0; i < 4; i++)                             \
        af[i] = *(const bf16x8*)&As[cur * 4096 + aOff[i]];                    \
    _Pragma("unroll") for (int j = 0; j < 4; j++)                             \
        bv[j] = *(const bf16x8*)&Bs[cur * 4096 + bOff[j]];                    \
    asm volatile("s_waitcnt lgkmcnt(0)" ::: "memory");                        \
    __builtin_amdgcn_s_barrier();          /* all waves done reading cur */   \
    __builtin_amdgcn_sched_barrier(0);                                        \
    if (ISSUE) {                                                              \
      const int ko = ((KT) + 3) * 32;                                         \
      const int bo = cur * 4096;                                              \
      GL16(gA1 + ko, laBase + bo);                                            \
      GL16(gA2 + ko, laBase + bo + 2048);                                     \
      GL16(gB1 + ko, lbBase + bo);                                            \
      GL16(gB2 + ko, lbBase + bo + 2048);                                     \
    }                                                                         \
    __builtin_amdgcn_s_setprio(1);                                            \
    _Pragma("unroll") for (int i = 0; i < 4; i++)                             \
      _Pragma("unroll") for (int j = 0; j < 4; j++)                           \
          acc[i][j] = __builtin_amdgcn_mfma_f32_16x16x32_bf16(                \
              af[i], bv[j], acc[i][j], 0, 0, 0);                              \
    __builtin_amdgcn_s_setprio(0);                                            \
    cur = (cur == 2) ? 0 : cur + 1;                                           \
  }

  for (int kt = 0; kt < 30; ++kt) GEMM_ITER(kt, "8", (kt < 29));
  GEMM_ITER(30, "4", false);
  GEMM_ITER(31, "0", false);
#undef GEMM_ITER

  const int rbase = (lane >> 4) * 4;
#pragma unroll
  for (int i = 0; i < 4; i++) {
#pragma unroll
    for (int j = 0; j < 4; j++) {
      const int col = n0 + wn + j * 16 + fr;
#pragma unroll
      for (int r = 0; r < 4; r++) {
        const int orow = wm + i * 16 + rbase + r;
        float v = acc[i][j][r];
        if (MODE == 0) v = v > 0.f ? v * v : 0.f;
        Cout[(size_t)(base + orow) * 1024 + col] = (bf16)v;
      }
    }
  }
}

// ---- combine: out[t] = w0*eo[s0] + w1*eo[s1] + eo[SB+t]. One block/token. ----
__global__ __launch_bounds__(256) void combine_kernel(
    const bf16* __restrict__ eo, const int* __restrict__ slotIdx,
    const float* __restrict__ wtok, float* __restrict__ out) {
  const int t = blockIdx.x;
  const int c = threadIdx.x * 4;
  const int s0 = slotIdx[t * 2], s1 = slotIdx[t * 2 + 1];
  const float w0 = wtok[t * 2], w1 = wtok[t * 2 + 1];
  union U { uint2 v; bf16 h[4]; };
  U a, b, sh;
  a.v  = *(const uint2*)(eo + (size_t)s0 * 1024 + c);
  b.v  = *(const uint2*)(eo + (size_t)s1 * 1024 + c);
  sh.v = *(const uint2*)(eo + (size_t)(SB + t) * 1024 + c);
  float4 o;
  o.x = w0 * (float)a.h[0] + w1 * (float)b.h[0] + (float)sh.h[0];
  o.y = w0 * (float)a.h[1] + w1 * (float)b.h[1] + (float)sh.h[1];
  o.z = w0 * (float)a.h[2] + w1 * (float)b.h[2] + (float)sh.h[2];
  o.w = w0 * (float)a.h[3] + w1 * (float)b.h[3] + (float)sh.h[3];
  *(float4*)(out + (size_t)t * 1024 + c) = o;
}

extern "C" void kernel_launch(void* const* d_in, const int* in_sizes, int n_in,
                              void* d_out, int out_size, void* d_ws,
                              size_t ws_size, hipStream_t stream) {
  const float* x     = (const float*)d_in[0];
  const float* gw    = (const float*)d_in[1];
  const float* lb    = (const float*)d_in[2];
  const float* w1    = (const float*)d_in[3];
  const float* w2    = (const float*)d_in[4];
  const float* cfc   = (const float*)d_in[5];
  const float* cproj = (const float*)d_in[6];
  float* out = (float*)d_out;
  char* ws = (char*)d_ws;

  int*   ntl   = (int*)(ws + WS_NTILES);
  int*   tE    = (int*)(ws + WS_TILE_E);
  int*   tB    = (int*)(ws + WS_TILE_BASE);
  int*   eidx  = (int*)(ws + WS_EIDX);
  float* wtok  = (float*)(ws + WS_WTOK);
  int*   tok   = (int*)(ws + WS_TOK);
  int*   slotI = (int*)(ws + WS_SLOT);
  bf16*  xg    = (bf16*)(ws + WS_XG);     // GEMM1 input; reused as eo for GEMM2 out
  bf16*  hid   = (bf16*)(ws + WS_HID);
  bf16*  w1b   = (bf16*)(ws + WS_W1B);
  bf16*  w2b   = (bf16*)(ws + WS_W2B);
  bf16*  cfcb  = (bf16*)(ws + WS_CFCB);
  bf16*  cprojb= (bf16*)(ws + WS_CPROJB);

  // router + (w1, cfc) conversion only — w2/cproj conversion rides inside GEMM1
  convrouter<<<5120, 256, 0, stream>>>(x, gw, lb, eidx, wtok, xg,
                                       w1, cfc, w1b, cfcb);
  assign_kernel<<<1, 256, 0, stream>>>(eidx, tE, tB, ntl, tok, slotI);

  moe_gemm<0><<<GEMM_BLKS + CONV2_BLKS, 256, 0, stream>>>(
      xg, w1b, cfcb, tE, tB, ntl, hid, tok, w2, cproj, w2b, cprojb);
  moe_gemm<1><<<GEMM_BLKS, 256, 0, stream>>>(
      hid, w2b, cprojb, tE, tB, ntl, xg, tok, nullptr, nullptr, nullptr, nullptr);
  combine_kernel<<<NTOK, 256, 0, stream>>>(xg, slotI, wtok, out);
}